// Round 1
// 124.336 us; speedup vs baseline: 1.3326x; 1.3326x over previous
//
#include <hip/hip_runtime.h>
#include <math.h>

#define NN 30000
#define BB 16
#define DD 32
#define KK 8
#define HH 8
#define DIST_C 5.0f
#define EPS_C 1e-6f
#define SCALE_C 0.17677669529663687f  // 1/sqrt(32)

// workspace layout (float offsets)
#define WS_ZMIN 0      // 16 x uint (encoded float)
#define WS_ZMAX 16     // 16 x uint
#define WS_ZSUM 32     // 32 f  [b*2+s]
#define WS_QW   64     // 32 f
#define WS_PK   96     // 256 f [h*32+d]
#define WS_WC   352    // 1024 f [d*32+e]
#define WS_T    1376   // 8192 f [b*512 + (s*8+h)*32 + d]
#define WS_AKG  9568   // 8192 f [b*512 + s*256 + h*32 + e]
#define WS_AVG  17760  // 8192 f

#define NPB 32   // nodes per block (8 threads per node, 256-thread blocks)

__device__ __forceinline__ unsigned fencode(float f) {
    unsigned u = __float_as_uint(f);
    return (u & 0x80000000u) ? ~u : (u | 0x80000000u);
}
__device__ __forceinline__ float fdecode(unsigned c) {
    return __uint_as_float((c & 0x80000000u) ? (c ^ 0x80000000u) : ~c);
}
__device__ __forceinline__ float silu(float x) { return x / (1.0f + expf(-x)); }

// edge[s][k] = sin(bw_k * x_s)/(x_s+eps); bw_k = (k+1)*bw0 (bw = linspace(pi,8pi,8))
// Chebyshev recurrence: s_{k+1} = 2cos(th)*s_k - s_{k-1}, th = bw0*x
__device__ __forceinline__ void bessel_edges(float bw0, float x0, float x1, float edge[2][8]) {
    float xs[2]; xs[0] = x0; xs[1] = x1;
    #pragma unroll
    for (int s = 0; s < 2; ++s) {
        float x = xs[s];
        float inv = 1.0f / (x + EPS_C);
        float th = bw0 * x;
        float c2 = 2.0f * cosf(th);
        float skm1 = 0.0f;
        float sk = sinf(th);
        #pragma unroll
        for (int k = 0; k < 8; ++k) {
            edge[s][k] = sk * inv;
            float nx = c2 * sk - skm1;
            skm1 = sk;
            sk = nx;
        }
    }
}

// ---------------------------------------------------------------- init
__global__ __launch_bounds__(256) void k_init(const float* __restrict__ init_dummy,
                                              const float* __restrict__ Wq_dummy,
                                              const float* __restrict__ Wdot,
                                              const float* __restrict__ W2_kd,
                                              const float* __restrict__ Wq_graph,
                                              float* __restrict__ ws) {
    __shared__ float qvec[32];
    __shared__ float qWl[32];
    int t = threadIdx.x;
    unsigned* wsu = (unsigned*)ws;
    if (t < 16) { wsu[WS_ZMIN + t] = 0xFFFFFFFFu; wsu[WS_ZMAX + t] = 0u; }
    if (t < 32) ws[WS_ZSUM + t] = 0.0f;
    for (int i = t; i < 8192; i += 256) ws[WS_T + i] = 0.0f;
    if (t < 32) {
        float acc = 0.0f;
        for (int d = 0; d < 32; ++d) acc += init_dummy[d] * Wq_dummy[d * 32 + t];
        qvec[t] = acc;
    }
    __syncthreads();
    if (t < 32) {
        float acc = 0.0f;
        for (int e = 0; e < 32; ++e) acc += qvec[e] * Wdot[e * 32 + t];
        qWl[t] = acc;
        ws[WS_QW + t] = acc;
    }
    __syncthreads();
    {   // P_k[h][d] = sum_e W2_kd[h,d*32+e] * qW[e]
        int h = t >> 5, d = t & 31;
        float acc = 0.0f;
        for (int e = 0; e < 32; ++e) acc += W2_kd[h * 1024 + d * 32 + e] * qWl[e];
        ws[WS_PK + t] = acc;
    }
    for (int i = t; i < 1024; i += 256) {  // Wcomb = Wq_graph @ Wdot
        int d = i >> 5, e = i & 31;
        float acc = 0.0f;
        for (int m = 0; m < 32; ++m) acc += Wq_graph[d * 32 + m] * Wdot[m * 32 + e];
        ws[WS_WC + i] = acc;
    }
}

// ---------------------------------------------------------------- z min/max per batch
__global__ __launch_bounds__(256) void k_zminmax(const float* __restrict__ pos,
                                                 const int* __restrict__ batch,
                                                 float* __restrict__ ws) {
    __shared__ unsigned zl[16], zh[16];
    int t = threadIdx.x;
    if (t < 16) { zl[t] = 0xFFFFFFFFu; zh[t] = 0u; }
    __syncthreads();
    int n = blockIdx.x * 256 + t;
    if (n < NN) {
        unsigned c = fencode(pos[3 * n + 2]);
        int b = batch[n];
        atomicMin(&zl[b], c);
        atomicMax(&zh[b], c);
    }
    __syncthreads();
    unsigned* wsu = (unsigned*)ws;
    if (t < 16) {
        if (zl[t] != 0xFFFFFFFFu) atomicMin(&wsu[WS_ZMIN + t], zl[t]);
        if (zh[t] != 0u)          atomicMax(&wsu[WS_ZMAX + t], zh[t]);
    }
}

// ---------------------------------------------------------------- phase 1
// 8 threads per node: t = li*8 + g, li = local node (0..31), g = dim group (4 dims).
// Fl row stride 36 floats (b128 writes: 8 consecutive lanes cover all 32 banks).
// Lw row stride 17 floats.
__global__ __launch_bounds__(256) void k_phase1(const float* __restrict__ pos,
                                                const int* __restrict__ batch,
                                                const float* __restrict__ nf,
                                                const float* __restrict__ bw,
                                                const float* __restrict__ W1_kd,
                                                const float* __restrict__ W1_vd,
                                                float* __restrict__ ws) {
    __shared__ __align__(16) float Fl[NPB * 36];
    __shared__ float Lw[NPB * 17];
    __shared__ int   Lb[NPB];
    __shared__ __align__(16) float Pk[256];
    __shared__ float W1kd[64], W1vd[64], zsl[32];
    int t = threadIdx.x;
    if (t < 64) { W1kd[t] = W1_kd[t]; W1vd[t] = W1_vd[t]; }
    Pk[t] = ws[WS_PK + t];
    if (t < 32) zsl[t] = 0.0f;

    int li = t >> 3, g = t & 7;
    int n0 = blockIdx.x * NPB;
    int n = n0 + li;
    bool valid = n < NN;
    float4 fv4 = make_float4(0.f, 0.f, 0.f, 0.f);
    int b = 0;
    if (valid) {
        b = batch[n];
        fv4 = ((const float4*)nf)[n * 8 + g];
        ((float4*)(Fl + li * 36))[g] = fv4;
        if (g == 0) Lb[li] = b;
    } else {
        if (g == 0) Lb[li] = -1;
    }
    __syncthreads();

    if (valid) {
        const unsigned* wsu = (const unsigned*)ws;
        float z = pos[3 * n + 2];
        float zmin = fdecode(wsu[WS_ZMIN + b]);
        float zmax = fdecode(wsu[WS_ZMAX + b]);
        float edge[2][8];
        bessel_edges(bw[0], z - zmin + DIST_C, zmax + DIST_C - z, edge);

        // u partials over my 4 dims: up[h] = fv4 . Pk[h][4g..4g+3]
        float up[8];
        const float4* Pk4 = (const float4*)Pk;
        #pragma unroll
        for (int h = 0; h < 8; ++h) {
            float4 p = Pk4[h * 8 + g];
            up[h] = fv4.x * p.x + fv4.y * p.y + fv4.z * p.z + fv4.w * p.w;
        }
        // my silu_kd (h = g) for both s, broadcast via shfl
        float kd0, kd1;
        {
            float p0 = 0.f, p1 = 0.f;
            #pragma unroll
            for (int k = 0; k < 8; ++k) {
                float w = W1kd[k * 8 + g];
                p0 += edge[0][k] * w;
                p1 += edge[1][k] * w;
            }
            kd0 = silu(p0); kd1 = silu(p1);
        }
        int lanebase = (t & 63) & 56;
        float sp0 = 0.f, sp1 = 0.f;
        #pragma unroll
        for (int h = 0; h < 8; ++h) {
            float a0 = __shfl(kd0, lanebase + h, 64);
            float a1 = __shfl(kd1, lanebase + h, 64);
            sp0 += a0 * up[h];
            sp1 += a1 * up[h];
        }
        #pragma unroll
        for (int m = 1; m < 8; m <<= 1) {
            sp0 += __shfl_xor(sp0, m, 64);
            sp1 += __shfl_xor(sp1, m, 64);
        }
        float ev0 = expf(sp0 * SCALE_C);
        float ev1 = expf(sp1 * SCALE_C);
        if (g == 0) {
            atomicAdd(&zsl[b * 2 + 0], ev0);
            atomicAdd(&zsl[b * 2 + 1], ev1);
        }
        // Lw[li][s*8+g] = ev_s * silu(pre_vd_s(h=g))
        float q0 = 0.f, q1 = 0.f;
        #pragma unroll
        for (int k = 0; k < 8; ++k) {
            float w = W1vd[k * 8 + g];
            q0 += edge[0][k] * w;
            q1 += edge[1][k] * w;
        }
        Lw[li * 17 + g]     = ev0 * silu(q0);
        Lw[li * 17 + 8 + g] = ev1 * silu(q1);
    }
    __syncthreads();
    if (t < 32 && zsl[t] != 0.0f) atomicAdd(&ws[WS_ZSUM + t], zsl[t]);

    // segment outer-product reduce: T[b][sh][d] += Lw[i][sh] * Fl[i][d]
    // thread owns (sh = t&15, d-pair dp = t>>4): 2 accumulators over 32 nodes.
    int count = NN - n0; if (count > NPB) count = NPB;
    int bf = Lb[0], bl = Lb[count - 1];
    int sh = t & 15, dp = t >> 4;
    for (int b2 = bf; b2 <= bl; ++b2) {
        float a0 = 0.f, a1 = 0.f;
        for (int i = 0; i < count; ++i) {
            if (Lb[i] != b2) continue;
            float w = Lw[i * 17 + sh];
            float2 x = *(const float2*)(Fl + i * 36 + 2 * dp);
            a0 += w * x.x;
            a1 += w * x.y;
        }
        float* Tb = ws + WS_T + b2 * 512 + sh * 32 + 2 * dp;
        atomicAdd(&Tb[0], a0);
        atomicAdd(&Tb[1], a1);
    }
}

// ---------------------------------------------------------------- per-(b,s): dummy_new, A_kg, A_vg
__global__ __launch_bounds__(256) void k_batch(const float* __restrict__ init_dummy,
                                               const float* __restrict__ W2_vd,
                                               const float* __restrict__ W2_kg,
                                               const float* __restrict__ W2_vg,
                                               float* __restrict__ ws) {
    int bs = blockIdx.x;
    int b = bs >> 1, s = bs & 1;
    int t = threadIdx.x;
    __shared__ float Tl[256];
    __shared__ float part[256];
    __shared__ float dn[32];
    Tl[t] = ws[WS_T + b * 512 + s * 256 + t];
    __syncthreads();
    {   // parallel dot: part[h*32+e] = sum_d Tl[h*32+d] * W2_vd[h,d*32+e]
        int h = t >> 5, e = t & 31;
        float acc = 0.0f;
        #pragma unroll
        for (int d = 0; d < 32; ++d) acc += Tl[h * 32 + d] * W2_vd[h * 1024 + d * 32 + e];
        part[t] = acc;
    }
    __syncthreads();
    if (t < 32) {
        float acc = 0.0f;
        #pragma unroll
        for (int h = 0; h < 8; ++h) acc += part[h * 32 + t];
        float zs = ws[WS_ZSUM + b * 2 + s];
        dn[t] = init_dummy[t] + acc / zs;
    }
    __syncthreads();
    {
        int h = t >> 5, e = t & 31;
        float ak = 0.0f, av = 0.0f;
        #pragma unroll
        for (int d = 0; d < 32; ++d) {
            float dv = dn[d];
            ak += dv * W2_kg[h * 1024 + d * 32 + e];
            av += dv * W2_vg[h * 1024 + d * 32 + e];
        }
        ws[WS_AKG + b * 512 + s * 256 + t] = ak;
        ws[WS_AVG + b * 512 + s * 256 + t] = av;
    }
}

// ---------------------------------------------------------------- finale: 8 threads per node
__global__ __launch_bounds__(256) void k_final(const float* __restrict__ pos,
                                               const int* __restrict__ batch,
                                               const float* __restrict__ nf,
                                               const float* __restrict__ bw,
                                               const float* __restrict__ W1_kg,
                                               const float* __restrict__ W1_vg,
                                               const float* __restrict__ ws,
                                               float* __restrict__ out) {
    __shared__ __align__(16) float Wc[1024];
    __shared__ __align__(16) float Fl[NPB * 36];
    __shared__ float W1kg[64], W1vg[64];
    int t = threadIdx.x;
    for (int i = t; i < 1024; i += 256) Wc[i] = ws[WS_WC + i];
    if (t < 64) { W1kg[t] = W1_kg[t]; W1vg[t] = W1_vg[t]; }

    int li = t >> 3, g = t & 7;
    int n0 = blockIdx.x * NPB;
    int n = n0 + li;
    bool valid = n < NN;
    float4 fv4 = make_float4(0.f, 0.f, 0.f, 0.f);
    if (valid) {
        fv4 = ((const float4*)nf)[n * 8 + g];
        ((float4*)(Fl + li * 36))[g] = fv4;
    }
    __syncthreads();
    if (!valid) return;  // whole 8-lane groups (and waves) drop out together

    int b = batch[n];
    const unsigned* wsu = (const unsigned*)ws;
    float z = pos[3 * n + 2];
    float zmin = fdecode(wsu[WS_ZMIN + b]);
    float zmax = fdecode(wsu[WS_ZMAX + b]);
    float edge[2][8];
    bessel_edges(bw[0], z - zmin + DIST_C, zmax + DIST_C - z, edge);

    // my silu_kg / silu_vg (h = g) for both s
    float ak0, ak1, av0, av1;
    {
        float pk0 = 0.f, pk1 = 0.f, pv0 = 0.f, pv1 = 0.f;
        #pragma unroll
        for (int k = 0; k < 8; ++k) {
            float wk = W1kg[k * 8 + g];
            float wv = W1vg[k * 8 + g];
            pk0 += edge[0][k] * wk; pk1 += edge[1][k] * wk;
            pv0 += edge[0][k] * wv; pv1 += edge[1][k] * wv;
        }
        ak0 = silu(pk0); ak1 = silu(pk1);
        av0 = silu(pv0); av1 = silu(pv1);
    }

    // full node features into regs (8x b128, bank-spread broadcast)
    float f[32];
    {
        const float4* myF4 = (const float4*)(Fl + li * 36);
        #pragma unroll
        for (int j = 0; j < 8; ++j) {
            float4 v = myF4[j];
            f[4 * j] = v.x; f[4 * j + 1] = v.y; f[4 * j + 2] = v.z; f[4 * j + 3] = v.w;
        }
    }
    // q slice: q4[e'] = sum_d f[d] * Wc[d][4g+e']
    float4 q4 = make_float4(0.f, 0.f, 0.f, 0.f);
    const float4* Wc4 = (const float4*)Wc;
    #pragma unroll
    for (int d = 0; d < 32; ++d) {
        float fd = f[d];
        float4 w = Wc4[d * 8 + g];
        q4.x += fd * w.x; q4.y += fd * w.y; q4.z += fd * w.z; q4.w += fd * w.w;
    }

    int lanebase = (t & 63) & 56;
    const float4* Ak4 = (const float4*)(ws + WS_AKG);
    const float4* Av4 = (const float4*)(ws + WS_AVG);
    float p0 = 0.f, p1 = 0.f;
    #pragma unroll
    for (int h = 0; h < 8; ++h) {
        float4 a0 = Ak4[b * 128 + h * 8 + g];
        float4 a1 = Ak4[b * 128 + 64 + h * 8 + g];
        float d0 = q4.x * a0.x + q4.y * a0.y + q4.z * a0.z + q4.w * a0.w;
        float d1 = q4.x * a1.x + q4.y * a1.y + q4.z * a1.z + q4.w * a1.w;
        p0 += __shfl(ak0, lanebase + h, 64) * d0;
        p1 += __shfl(ak1, lanebase + h, 64) * d1;
    }
    #pragma unroll
    for (int m = 1; m < 8; m <<= 1) {
        p0 += __shfl_xor(p0, m, 64);
        p1 += __shfl_xor(p1, m, 64);
    }
    float sg0 = p0 * SCALE_C, sg1 = p1 * SCALE_C;
    float mm = fmaxf(sg0, sg1);
    float e0 = expf(sg0 - mm), e1 = expf(sg1 - mm);
    float inv = 1.0f / (e0 + e1);
    float ag0 = e0 * inv, ag1 = e1 * inv;

    float4 x4 = fv4;
    #pragma unroll
    for (int h = 0; h < 8; ++h) {
        float w0 = ag0 * __shfl(av0, lanebase + h, 64);
        float w1 = ag1 * __shfl(av1, lanebase + h, 64);
        float4 a0 = Av4[b * 128 + h * 8 + g];
        float4 a1 = Av4[b * 128 + 64 + h * 8 + g];
        x4.x += w0 * a0.x + w1 * a1.x;
        x4.y += w0 * a0.y + w1 * a1.y;
        x4.z += w0 * a0.z + w1 * a1.z;
        x4.w += w0 * a0.w + w1 * a1.w;
    }
    ((float4*)out)[n * 8 + g] = x4;
}

extern "C" void kernel_launch(void* const* d_in, const int* in_sizes, int n_in,
                              void* d_out, int out_size, void* d_ws, size_t ws_size,
                              hipStream_t stream) {
    const float* pos        = (const float*)d_in[0];
    const float* nf         = (const float*)d_in[1];
    const int*   batch      = (const int*)d_in[2];
    const float* bw         = (const float*)d_in[3];
    const float* init_dummy = (const float*)d_in[4];
    const float* Wq_dummy   = (const float*)d_in[5];
    const float* Wq_graph   = (const float*)d_in[6];
    const float* Wdot       = (const float*)d_in[7];
    const float* W1_kd      = (const float*)d_in[8];
    const float* W2_kd      = (const float*)d_in[9];
    const float* W1_vd      = (const float*)d_in[10];
    const float* W2_vd      = (const float*)d_in[11];
    const float* W1_kg      = (const float*)d_in[12];
    const float* W2_kg      = (const float*)d_in[13];
    const float* W1_vg      = (const float*)d_in[14];
    const float* W2_vg      = (const float*)d_in[15];
    float* ws  = (float*)d_ws;
    float* out = (float*)d_out;

    int nblk1 = (NN + 255) / 256;            // zminmax: 1 thread/node
    int nblk8 = (NN + NPB - 1) / NPB;        // phase1/final: 8 threads/node
    hipLaunchKernelGGL(k_init, dim3(1), dim3(256), 0, stream,
                       init_dummy, Wq_dummy, Wdot, W2_kd, Wq_graph, ws);
    hipLaunchKernelGGL(k_zminmax, dim3(nblk1), dim3(256), 0, stream, pos, batch, ws);
    hipLaunchKernelGGL(k_phase1, dim3(nblk8), dim3(256), 0, stream,
                       pos, batch, nf, bw, W1_kd, W1_vd, ws);
    hipLaunchKernelGGL(k_batch, dim3(32), dim3(256), 0, stream,
                       init_dummy, W2_vd, W2_kg, W2_vg, ws);
    hipLaunchKernelGGL(k_final, dim3(nblk8), dim3(256), 0, stream,
                       pos, batch, nf, bw, W1_kg, W1_vg, ws, out);
}